// Round 3
// baseline (559.091 us; speedup 1.0000x reference)
//
#include <hip/hip_runtime.h>
#include <hip/hip_bf16.h>

// ============================================================================
// 2-layer LSTM cell + FF head, B=32768, IN=64, H=256, OUT=768.
// DTYPE (R2 final): ALL inputs f32, d_out f32. bf16 only internally (MFMA),
// licensed by the bf16-floor threshold (8*2^-8*max|ref|).
//   R0 NaN     = f32 weights misread as bf16.
//   R1 absmax 3.57 = bf16 written into f32-read d_out (pair-fusion garbage).
//
// d_in order: 0 inp[32768,64] 1 state1[32768,512] 2 state2[32768,512]
//  3 l1_wf 4 l1_bf 5 l2_wf 6 l2_bf | 7 l1_wk 8 l1_bk 9 l2_wk 10 l2_bk
// 11 l1_wi 12 l1_bi 13 l2_wi 14 l2_bi | 15 l1_ws 16 l1_bs 17 l2_ws 18 l2_bs
// 19 ff_w[256,768]   (all float32)
//
// d_out (f32, concat): means[B,256] | deviances[B,256] | mult[B,256]
//                      | new_state1[B,512] | new_state2[B,512]
// ============================================================================

typedef __attribute__((ext_vector_type(8))) short short8;    // 8 bf16 = 4 VGPRs
typedef __attribute__((ext_vector_type(4))) short short4_t;  // 4 bf16 = 8 B
typedef __attribute__((ext_vector_type(4))) float floatx4;   // MFMA acc

#define BATCH 32768

static const size_t DEV_OFF  = (size_t)BATCH * 256;          // f32 elems
static const size_t MULT_OFF = (size_t)2 * BATCH * 256;
static const size_t NS1_OFF  = (size_t)3 * BATCH * 256;
static const size_t NS2_OFF  = NS1_OFF + (size_t)BATCH * 512;

__device__ __forceinline__ unsigned short f2bf(float f) {
    union { float f; unsigned int i; } v; v.f = f;
    unsigned int i = v.i;
    i += 0x7fff + ((i >> 16) & 1);   // RNE
    return (unsigned short)(i >> 16);
}
__device__ __forceinline__ float sigmoidf_(float x) {
    return 1.f / (1.f + __expf(-x));
}

// ---------------------------------------------------------------------------
// Weight repack: f32 -> bf16, n-major, so B-fragments are contiguous in k.
// ws layout (ushort): W1p[4][256][320] | W2p[4][256][512] | W3p[768][256]
// ---------------------------------------------------------------------------
#define W1P_ELEMS (4 * 256 * 320)
#define W2P_ELEMS (4 * 256 * 512)
#define W3P_ELEMS (768 * 256)

__global__ void pack_w(
    const float* __restrict__ a0, const float* __restrict__ a1,
    const float* __restrict__ a2, const float* __restrict__ a3,
    const float* __restrict__ c0, const float* __restrict__ c1,
    const float* __restrict__ c2, const float* __restrict__ c3,
    const float* __restrict__ fw,
    unsigned short* __restrict__ dst)
{
    int idx = blockIdx.x * 256 + threadIdx.x;   // grid covers exactly W1+W2+W3
    if (idx < W1P_ELEMS) {
        int g = idx / (256 * 320), rem = idx % (256 * 320);
        int n = rem / 320, k = rem % 320;
        const float* s = g == 0 ? a0 : g == 1 ? a1 : g == 2 ? a2 : a3;
        dst[idx] = f2bf(s[k * 256 + n]);
    } else if (idx < W1P_ELEMS + W2P_ELEMS) {
        int j = idx - W1P_ELEMS;
        int g = j / (256 * 512), rem = j % (256 * 512);
        int n = rem / 512, k = rem % 512;
        const float* s = g == 0 ? c0 : g == 1 ? c1 : g == 2 ? c2 : c3;
        dst[idx] = f2bf(s[k * 256 + n]);
    } else {
        int j = idx - (W1P_ELEMS + W2P_ELEMS);
        int n = j / 256, k = j % 256;
        dst[idx] = f2bf(fw[k * 768 + n]);
    }
}

// ---------------------------------------------------------------------------
// LSTM layer. Block = 256 thr (4 waves); tile 64 rows x 64 h; wave g owns
// gate g's 64x64 pre-activation via 16 MFMA 16x16x32 tiles.
// X = concat(x0[:, :x0_cols], state[:, :256]); KTOT = x0_cols + 256.
// All activations f32 in global; converted to bf16 while staging to LDS.
// ---------------------------------------------------------------------------
template<int KTOT>
__global__ __launch_bounds__(256) void lstm_layer_k(
    const float* __restrict__ x0, int x0_stride, int x0_cols,
    const float* __restrict__ state,              // [B][512] f32: out|cell
    const unsigned short* __restrict__ wp,        // [4][256][KTOT] bf16 n-major
    const float* __restrict__ bias0, const float* __restrict__ bias1,
    const float* __restrict__ bias2, const float* __restrict__ bias3,
    float* __restrict__ nstate)                   // [B][512] f32
{
    __shared__ __align__(16) union {
        struct {
            unsigned short xs[64][72];      // 64 rows x 64 k (+8 pad)
            unsigned short ws[4][64][72];   // gate, n, k (+8 pad)
        } st;
        float s[64][260];                   // gate pre-activations
    } lds;

    const int tid  = threadIdx.x;
    const int wave = tid >> 6;
    const int lane = tid & 63;
    const int lhi  = lane >> 4, llo = lane & 15;
    const int row0 = blockIdx.x * 64;
    const int jt   = blockIdx.y * 64;

    floatx4 acc[4][4];
#pragma unroll
    for (int i = 0; i < 4; i++)
#pragma unroll
        for (int j = 0; j < 4; j++) acc[i][j] = (floatx4){0.f, 0.f, 0.f, 0.f};

    for (int c = 0; c < KTOT / 64; ++c) {
        const int kbase = c * 64;
        // --- stage X chunk (64 rows x 64 k): f32 -> bf16 ---
        {
            const float* src; int scol, sstr;
            if (kbase < x0_cols) { src = x0;   scol = kbase;           sstr = x0_stride; }
            else                 { src = state; scol = kbase - x0_cols; sstr = 512; }
            const int l4 = tid & 15; const int r0 = tid >> 4;
#pragma unroll
            for (int p = 0; p < 4; ++p) {
                int r = r0 + p * 16;
                float4 v = *(const float4*)(src + (size_t)(row0 + r) * sstr + scol + l4 * 4);
                short4_t h;
                h.x = (short)f2bf(v.x); h.y = (short)f2bf(v.y);
                h.z = (short)f2bf(v.z); h.w = (short)f2bf(v.w);
                *(short4_t*)&lds.st.xs[r][l4 * 4] = h;
            }
        }
        // --- stage W chunk: wave g loads its gate's 64n x 64k (bf16) ---
        {
            const int l8 = lane & 7, nr = lane >> 3;
            const unsigned short* wsrc = wp + ((size_t)wave * 256 + jt) * KTOT + kbase;
#pragma unroll
            for (int p = 0; p < 8; ++p) {
                int n = p * 8 + nr;
                *(uint4*)&lds.st.ws[wave][n][l8 * 8] =
                    *(const uint4*)(wsrc + (size_t)n * KTOT + l8 * 8);
            }
        }
        __syncthreads();
        // --- compute: 2 k-steps of 32 ---
#pragma unroll
        for (int ks = 0; ks < 2; ++ks) {
            const int k8 = ks * 32 + lhi * 8;
            short8 a[4], b[4];
#pragma unroll
            for (int mi = 0; mi < 4; mi++)
                a[mi] = *(const short8*)&lds.st.xs[mi * 16 + llo][k8];
#pragma unroll
            for (int ni = 0; ni < 4; ni++)
                b[ni] = *(const short8*)&lds.st.ws[wave][ni * 16 + llo][k8];
#pragma unroll
            for (int mi = 0; mi < 4; mi++)
#pragma unroll
                for (int ni = 0; ni < 4; ni++)
                    acc[mi][ni] = __builtin_amdgcn_mfma_f32_16x16x32_bf16(
                        a[mi], b[ni], acc[mi][ni], 0, 0, 0);
        }
        __syncthreads();
    }

    // --- bias add + dump gate pre-activations to LDS (f32) ---
    {
        const float* bp = wave == 0 ? bias0 : wave == 1 ? bias1
                        : wave == 2 ? bias2 : bias3;
#pragma unroll
        for (int ni = 0; ni < 4; ni++) {
            float bv = bp[jt + ni * 16 + llo];
#pragma unroll
            for (int mi = 0; mi < 4; mi++)
#pragma unroll
                for (int r = 0; r < 4; r++) {
                    int m = mi * 16 + lhi * 4 + r;
                    lds.s[m][wave * 64 + ni * 16 + llo] = acc[mi][ni][r] + bv;
                }
        }
    }
    __syncthreads();

    // --- elementwise LSTM cell update; write out|cell (f32) to nstate ---
    for (int it = 0; it < 16; ++it) {
        int e = tid + it * 256;
        int r = e >> 6, h = e & 63;
        float zf = lds.s[r][h];
        float zk = lds.s[r][64 + h];
        float zi = lds.s[r][128 + h];
        float zs = lds.s[r][192 + h];
        float rst = sigmoidf_(zf);
        float wrt = sigmoidf_(zk);
        float itm = tanhf(zi);
        float rd  = sigmoidf_(zs);
        size_t rowel = (size_t)(row0 + r) * 512;
        float cold = state[rowel + 256 + jt + h];
        float cell = rst * cold + wrt * itm;
        float o = rd * tanhf(cell);
        nstate[rowel + jt + h]       = o;
        nstate[rowel + 256 + jt + h] = cell;
    }
}

// ---------------------------------------------------------------------------
// FF head: out2[B,256] (f32, = new_state2[:, :256] in d_out) @ ff_w + epilogue.
// grid.y: 0 -> means (identity), 1 -> deviances (exp), 2 -> mult (softmax/HM).
// ---------------------------------------------------------------------------
__global__ __launch_bounds__(256) void ff_k(
    const float* __restrict__ x,             // new_state2 base, stride 512 f32
    const unsigned short* __restrict__ wp,   // [768][256] bf16 n-major
    float* __restrict__ out)
{
    __shared__ __align__(16) union {
        struct {
            unsigned short xs[64][72];
            unsigned short ws[4][64][72];
        } st;
        float s[64][260];
    } lds;

    const int tid  = threadIdx.x;
    const int wave = tid >> 6;
    const int lane = tid & 63;
    const int lhi  = lane >> 4, llo = lane & 15;
    const int row0  = blockIdx.x * 64;
    const int ncol0 = blockIdx.y * 256;

    floatx4 acc[4][4];
#pragma unroll
    for (int i = 0; i < 4; i++)
#pragma unroll
        for (int j = 0; j < 4; j++) acc[i][j] = (floatx4){0.f, 0.f, 0.f, 0.f};

    for (int c = 0; c < 4; ++c) {
        const int kbase = c * 64;
        // --- stage X chunk: f32 -> bf16 ---
        {
            const int l4 = tid & 15; const int r0 = tid >> 4;
#pragma unroll
            for (int p = 0; p < 4; ++p) {
                int r = r0 + p * 16;
                float4 v = *(const float4*)(x + (size_t)(row0 + r) * 512 + kbase + l4 * 4);
                short4_t h;
                h.x = (short)f2bf(v.x); h.y = (short)f2bf(v.y);
                h.z = (short)f2bf(v.z); h.w = (short)f2bf(v.w);
                *(short4_t*)&lds.st.xs[r][l4 * 4] = h;
            }
        }
        // --- stage W chunk ---
        {
            const int l8 = lane & 7, nr = lane >> 3;
            const unsigned short* wsrc = wp + (size_t)(ncol0 + wave * 64) * 256 + kbase;
#pragma unroll
            for (int p = 0; p < 8; ++p) {
                int n = p * 8 + nr;
                *(uint4*)&lds.st.ws[wave][n][l8 * 8] =
                    *(const uint4*)(wsrc + (size_t)n * 256 + l8 * 8);
            }
        }
        __syncthreads();
#pragma unroll
        for (int ks = 0; ks < 2; ++ks) {
            const int k8 = ks * 32 + lhi * 8;
            short8 a[4], b[4];
#pragma unroll
            for (int mi = 0; mi < 4; mi++)
                a[mi] = *(const short8*)&lds.st.xs[mi * 16 + llo][k8];
#pragma unroll
            for (int ni = 0; ni < 4; ni++)
                b[ni] = *(const short8*)&lds.st.ws[wave][ni * 16 + llo][k8];
#pragma unroll
            for (int mi = 0; mi < 4; mi++)
#pragma unroll
                for (int ni = 0; ni < 4; ni++)
                    acc[mi][ni] = __builtin_amdgcn_mfma_f32_16x16x32_bf16(
                        a[mi], b[ni], acc[mi][ni], 0, 0, 0);
        }
        __syncthreads();
    }

    if (blockIdx.y < 2) {
        const size_t obase = (blockIdx.y == 0) ? (size_t)0 : DEV_OFF;
        const bool doexp = (blockIdx.y == 1);
#pragma unroll
        for (int mi = 0; mi < 4; mi++)
#pragma unroll
            for (int ni = 0; ni < 4; ni++) {
                int cc = wave * 64 + ni * 16 + llo;
#pragma unroll
                for (int r = 0; r < 4; r++) {
                    int m = mi * 16 + lhi * 4 + r;
                    float v = acc[mi][ni][r];
                    if (doexp) v = __expf(v);
                    out[obase + (size_t)(row0 + m) * 256 + cc] = v;
                }
            }
    } else {
        // mult: softmax across HM=4 groups; col = m*64 + t, softmax over m.
#pragma unroll
        for (int mi = 0; mi < 4; mi++)
#pragma unroll
            for (int ni = 0; ni < 4; ni++)
#pragma unroll
                for (int r = 0; r < 4; r++) {
                    int m = mi * 16 + lhi * 4 + r;
                    lds.s[m][wave * 64 + ni * 16 + llo] = acc[mi][ni][r];
                }
        __syncthreads();
        for (int it = 0; it < 16; ++it) {
            int e = tid + it * 256;
            int r = e >> 6, t = e & 63;
            float v0 = lds.s[r][t];
            float v1 = lds.s[r][64 + t];
            float v2 = lds.s[r][128 + t];
            float v3 = lds.s[r][192 + t];
            float mx = fmaxf(fmaxf(v0, v1), fmaxf(v2, v3));
            float e0 = __expf(v0 - mx), e1 = __expf(v1 - mx);
            float e2 = __expf(v2 - mx), e3 = __expf(v3 - mx);
            float inv = 1.f / (e0 + e1 + e2 + e3);
            size_t base = MULT_OFF + (size_t)(row0 + r) * 256 + t;
            out[base]       = e0 * inv;
            out[base + 64]  = e1 * inv;
            out[base + 128] = e2 * inv;
            out[base + 192] = e3 * inv;
        }
    }
}

// ---------------------------------------------------------------------------
extern "C" void kernel_launch(void* const* d_in, const int* in_sizes, int n_in,
                              void* d_out, int out_size, void* d_ws, size_t ws_size,
                              hipStream_t stream)
{
    typedef const float* cfp;
    cfp inp = (cfp)d_in[0];
    cfp st1 = (cfp)d_in[1];
    cfp st2 = (cfp)d_in[2];
    cfp l1w0 = (cfp)d_in[3],  l1w1 = (cfp)d_in[7],  l1w2 = (cfp)d_in[11], l1w3 = (cfp)d_in[15];
    cfp l1b0 = (cfp)d_in[4],  l1b1 = (cfp)d_in[8],  l1b2 = (cfp)d_in[12], l1b3 = (cfp)d_in[16];
    cfp l2w0 = (cfp)d_in[5],  l2w1 = (cfp)d_in[9],  l2w2 = (cfp)d_in[13], l2w3 = (cfp)d_in[17];
    cfp l2b0 = (cfp)d_in[6],  l2b1 = (cfp)d_in[10], l2b2 = (cfp)d_in[14], l2b3 = (cfp)d_in[18];
    cfp ffw = (cfp)d_in[19];

    float* out = (float*)d_out;
    unsigned short* ws = (unsigned short*)d_ws;

    const size_t W1P = 0;
    const size_t W2P = W1P + W1P_ELEMS;
    const size_t W3P = W2P + W2P_ELEMS;

    // repack weights f32 -> bf16 n-major: 1,048,576 elems = 4096 blocks
    pack_w<<<4096, 256, 0, stream>>>(l1w0, l1w1, l1w2, l1w3,
                                     l2w0, l2w1, l2w2, l2w3, ffw, ws);

    // layer 1: X = [inp(64) | state1.out(256)], K=320
    lstm_layer_k<320><<<dim3(512, 4), 256, 0, stream>>>(
        inp, 64, 64, st1, ws + W1P, l1b0, l1b1, l1b2, l1b3, out + NS1_OFF);

    // layer 2: X = [out1(256, f32 in d_out) | state2.out(256)], K=512
    lstm_layer_k<512><<<dim3(512, 4), 256, 0, stream>>>(
        out + NS1_OFF, 512, 256, st2, ws + W2P, l2b0, l2b1, l2b2, l2b3,
        out + NS2_OFF);

    // FF head + epilogues; out2 = new_state2[:, :256] (f32, in d_out)
    ff_k<<<dim3(512, 3), 256, 0, stream>>>(out + NS2_OFF, ws + W3P, out);
}